// Round 1
// baseline (278.984 us; speedup 1.0000x reference)
//
#include <hip/hip_runtime.h>
#include <hip/hip_bf16.h>

typedef __bf16 bf16x8 __attribute__((ext_vector_type(8)));
typedef float f32x4 __attribute__((ext_vector_type(4)));
typedef unsigned short u16x8 __attribute__((ext_vector_type(8)));

#define MFMA16(a, b, c) __builtin_amdgcn_mfma_f32_16x16x32_bf16(a, b, c, 0, 0, 0)

// round-to-nearest-even fp32 -> bf16 (finite inputs only)
static __device__ __forceinline__ unsigned short f2bf(float f) {
    unsigned int u = __float_as_uint(f);
    u += 0x7fffu + ((u >> 16) & 1u);
    return (unsigned short)(u >> 16);
}

// ---------------------------------------------------------------------------
// Tiled transpose + fp32->bf16 cast: in [R x C] fp32 -> out [C x R] bf16
// ---------------------------------------------------------------------------
__global__ __launch_bounds__(256) void transpose_cast_k(
    const float* __restrict__ in, unsigned short* __restrict__ out, int R, int C) {
    __shared__ float t[32][33];
    int c0 = blockIdx.x * 32, r0 = blockIdx.y * 32;
    int tr = threadIdx.x >> 5, tc = threadIdx.x & 31;
#pragma unroll
    for (int i = 0; i < 4; i++)
        t[tr + i * 8][tc] = in[(size_t)(r0 + tr + i * 8) * C + c0 + tc];
    __syncthreads();
#pragma unroll
    for (int i = 0; i < 4; i++)
        out[(size_t)(c0 + tr + i * 8) * R + r0 + tc] = f2bf(t[tc][tr + i * 8]);
}

// ---------------------------------------------------------------------------
// RMSNorm (F.normalize * sqrt(dim) * gamma), fp32 in -> bf16 out. Row = 1024.
// ---------------------------------------------------------------------------
__global__ __launch_bounds__(256) void rmsnorm_k(
    const float* __restrict__ x, const float* __restrict__ gamma,
    unsigned short* __restrict__ xn) {
    int row = blockIdx.x;
    int tid = threadIdx.x;
    const float* xr = x + (size_t)row * 1024;
    float4 v = *(const float4*)(xr + tid * 4);
    float ss = v.x * v.x + v.y * v.y + v.z * v.z + v.w * v.w;
#pragma unroll
    for (int off = 1; off < 64; off <<= 1) ss += __shfl_xor(ss, off, 64);
    __shared__ float red[4];
    if ((tid & 63) == 0) red[tid >> 6] = ss;
    __syncthreads();
    float tot = red[0] + red[1] + red[2] + red[3];
    float f = 32.0f / fmaxf(sqrtf(tot), 1e-12f);  // sqrt(1024)=32
    float4 g = *(const float4*)(gamma + tid * 4);
    ushort4 o;
    o.x = f2bf(v.x * f * g.x);
    o.y = f2bf(v.y * f * g.y);
    o.z = f2bf(v.z * f * g.z);
    o.w = f2bf(v.w * f * g.w);
    *(ushort4*)(xn + (size_t)row * 1024 + tid * 4) = o;
}

// ---------------------------------------------------------------------------
// GEMM: C[M,N] = A[M,K] * BT[N,K]^T, bf16 inputs, fp32 accumulate.
// 128x128 block tile, 4 waves (2x2), each wave 64x64 = 4x4 mfma 16x16x32.
// MODE 0: fp32 store to C.  MODE 1: qkv scatter epilogue (bf16 q*scale,k,v).
// ---------------------------------------------------------------------------
template <int MODE>
__global__ __launch_bounds__(256) void gemm_bt_k(
    const unsigned short* __restrict__ A, const unsigned short* __restrict__ BT,
    float* __restrict__ C, unsigned short* __restrict__ qw,
    unsigned short* __restrict__ kw, unsigned short* __restrict__ vw,
    int M, int N, int K) {
    __shared__ unsigned short As[128][40];  // stride 40: 16B-aligned rows, ~2-way banks
    __shared__ unsigned short Bs[128][40];
    int tid = threadIdx.x;
    int wave = tid >> 6, lane = tid & 63, quad = lane >> 4, l16 = lane & 15;
    int wr = wave >> 1, wc = wave & 1;
    int m0 = blockIdx.y * 128, n0 = blockIdx.x * 128;
    int srow = tid >> 2, skc = (tid & 3) * 8;
    const unsigned short* Ag = A + (size_t)(m0 + srow) * K + skc;
    const unsigned short* Bg = BT + (size_t)(n0 + srow) * K + skc;
    f32x4 acc[4][4] = {};
    for (int k0 = 0; k0 < K; k0 += 32) {
        *(u16x8*)&As[srow][skc] = *(const u16x8*)(Ag + k0);
        *(u16x8*)&As[srow + 64][skc] = *(const u16x8*)(Ag + (size_t)64 * K + k0);
        *(u16x8*)&Bs[srow][skc] = *(const u16x8*)(Bg + k0);
        *(u16x8*)&Bs[srow + 64][skc] = *(const u16x8*)(Bg + (size_t)64 * K + k0);
        __syncthreads();
        bf16x8 af[4], bfr[4];
#pragma unroll
        for (int t = 0; t < 4; t++) {
            af[t] = *(const bf16x8*)&As[wr * 64 + t * 16 + l16][quad * 8];
            bfr[t] = *(const bf16x8*)&Bs[wc * 64 + t * 16 + l16][quad * 8];
        }
#pragma unroll
        for (int rt = 0; rt < 4; rt++)
#pragma unroll
            for (int ct = 0; ct < 4; ct++)
                acc[rt][ct] = MFMA16(af[rt], bfr[ct], acc[rt][ct]);
        __syncthreads();
    }
#pragma unroll
    for (int rt = 0; rt < 4; rt++) {
#pragma unroll
        for (int ct = 0; ct < 4; ct++) {
#pragma unroll
            for (int r = 0; r < 4; r++) {
                int m = m0 + wr * 64 + rt * 16 + quad * 4 + r;
                int col = n0 + wc * 64 + ct * 16 + l16;
                float vv = acc[rt][ct][r];
                if (MODE == 0) {
                    C[(size_t)m * N + col] = vv;
                } else {
                    // col -> (section, head, d);  m -> (batch, token)
                    int sec = col >> 10, ci = col & 1023;
                    int hh = ci >> 6, dd = ci & 63;
                    int b = m >> 11, nn = m & 2047;
                    size_t idx = (((size_t)(b * 16 + hh)) * 2048 + nn) * 64 + dd;
                    if (sec == 0) qw[idx] = f2bf(vv * 0.125f);  // scale = 64^-0.5
                    else if (sec == 1) kw[idx] = f2bf(vv);
                    else vw[idx] = f2bf(vv);
                }
            }
        }
    }
}

// ---------------------------------------------------------------------------
// Causal flash attention. q,k,v: [32 (b*h)][2048][64] bf16 (q pre-scaled).
// o: [4096][1024] bf16 (token-major, col = h*64+d).
// Block: 128 q-rows, 4 waves x 32 rows. K-tiles of 64, online softmax.
// ---------------------------------------------------------------------------
__global__ __launch_bounds__(256) void attn_k(
    const unsigned short* __restrict__ q, const unsigned short* __restrict__ k,
    const unsigned short* __restrict__ v, unsigned short* __restrict__ o) {
    __shared__ unsigned short Ks[64][72];      // [key][d], stride 72 (16B-aligned)
    __shared__ unsigned short Vt[64][72];      // [d][key], transposed at stage time
    __shared__ unsigned short Ps[4][32][72];   // per-wave P round-trip
    int bh = blockIdx.y;
    int qb = blockIdx.x * 128;
    int tid = threadIdx.x, wave = tid >> 6, lane = tid & 63;
    int quad = lane >> 4, l16 = lane & 15;
    const unsigned short* qg = q + ((size_t)bh * 2048) * 64;
    const unsigned short* kgb = k + ((size_t)bh * 2048) * 64;
    const unsigned short* vgb = v + ((size_t)bh * 2048) * 64;
    int qw0 = qb + wave * 32;
    bf16x8 aq[2][2];
#pragma unroll
    for (int rt = 0; rt < 2; rt++)
#pragma unroll
        for (int ks = 0; ks < 2; ks++)
            aq[rt][ks] = *(const bf16x8*)&qg[(size_t)(qw0 + rt * 16 + l16) * 64 + ks * 32 + quad * 8];
    f32x4 oacc[2][4] = {};
    float mrun[2][4], lrun[2][4];
#pragma unroll
    for (int rt = 0; rt < 2; rt++)
#pragma unroll
        for (int r = 0; r < 4; r++) { mrun[rt][r] = -1e30f; lrun[rt][r] = 0.f; }
    int nkt = qb / 64 + 2;  // causal: only tiles up to block diagonal
    int srow = tid >> 2, sd0 = (tid & 3) * 16;
    for (int kt = 0; kt < nkt; kt++) {
        __syncthreads();  // previous PV reads done before restage
        const unsigned short* kg = kgb + (size_t)(kt * 64) * 64;
        const unsigned short* vg = vgb + (size_t)(kt * 64) * 64;
        *(u16x8*)&Ks[srow][sd0] = *(const u16x8*)&kg[srow * 64 + sd0];
        *(u16x8*)&Ks[srow][sd0 + 8] = *(const u16x8*)&kg[srow * 64 + sd0 + 8];
        u16x8 v0 = *(const u16x8*)&vg[srow * 64 + sd0];
        u16x8 v1 = *(const u16x8*)&vg[srow * 64 + sd0 + 8];
#pragma unroll
        for (int j = 0; j < 8; j++) {
            Vt[sd0 + j][srow] = v0[j];
            Vt[sd0 + 8 + j][srow] = v1[j];
        }
        __syncthreads();
        // S = Q * K^T  (2 row-tiles x 4 col-tiles, K-dim 64 = 2 mfma steps)
        f32x4 sf[2][4] = {};
#pragma unroll
        for (int ct = 0; ct < 4; ct++) {
            bf16x8 b0 = *(const bf16x8*)&Ks[ct * 16 + l16][quad * 8];
            bf16x8 b1 = *(const bf16x8*)&Ks[ct * 16 + l16][32 + quad * 8];
#pragma unroll
            for (int rt = 0; rt < 2; rt++) {
                sf[rt][ct] = MFMA16(aq[rt][0], b0, sf[rt][ct]);
                sf[rt][ct] = MFMA16(aq[rt][1], b1, sf[rt][ct]);
            }
        }
        // causal mask (wave-uniform predicate; tiles fully below diag skip it)
        if (kt * 64 + 63 > qw0) {
#pragma unroll
            for (int rt = 0; rt < 2; rt++)
#pragma unroll
                for (int r = 0; r < 4; r++) {
                    int qrow = qw0 + rt * 16 + quad * 4 + r;
#pragma unroll
                    for (int ct = 0; ct < 4; ct++) {
                        int kcol = kt * 64 + ct * 16 + l16;
                        if (kcol > qrow) sf[rt][ct][r] = -1e30f;
                    }
                }
        }
        // online softmax: row reductions across the 16 lanes of each quad-row
        float alpha[2][4];
#pragma unroll
        for (int rt = 0; rt < 2; rt++) {
#pragma unroll
            for (int r = 0; r < 4; r++) {
                float mx = fmaxf(fmaxf(sf[rt][0][r], sf[rt][1][r]),
                                 fmaxf(sf[rt][2][r], sf[rt][3][r]));
#pragma unroll
                for (int off = 1; off < 16; off <<= 1) mx = fmaxf(mx, __shfl_xor(mx, off, 16));
                float mnew = fmaxf(mrun[rt][r], mx);
                float al = __expf(mrun[rt][r] - mnew);
                mrun[rt][r] = mnew;
                float rs = 0.f;
#pragma unroll
                for (int ct = 0; ct < 4; ct++) {
                    float p = __expf(sf[rt][ct][r] - mnew);
                    sf[rt][ct][r] = p;
                    rs += p;
                }
#pragma unroll
                for (int off = 1; off < 16; off <<= 1) rs += __shfl_xor(rs, off, 16);
                lrun[rt][r] = lrun[rt][r] * al + rs;
                alpha[rt][r] = al;
            }
        }
        // rescale O, write P (C-layout) to LDS for A-operand reload
#pragma unroll
        for (int rt = 0; rt < 2; rt++)
#pragma unroll
            for (int ct = 0; ct < 4; ct++)
#pragma unroll
                for (int r = 0; r < 4; r++) {
                    oacc[rt][ct][r] *= alpha[rt][r];
                    Ps[wave][rt * 16 + quad * 4 + r][ct * 16 + l16] = f2bf(sf[rt][ct][r]);
                }
        __syncthreads();
        // O += P * V
#pragma unroll
        for (int ks = 0; ks < 2; ks++) {
            bf16x8 ap0 = *(const bf16x8*)&Ps[wave][l16][ks * 32 + quad * 8];
            bf16x8 ap1 = *(const bf16x8*)&Ps[wave][16 + l16][ks * 32 + quad * 8];
#pragma unroll
            for (int ct = 0; ct < 4; ct++) {
                bf16x8 bv = *(const bf16x8*)&Vt[ct * 16 + l16][ks * 32 + quad * 8];
                oacc[0][ct] = MFMA16(ap0, bv, oacc[0][ct]);
                oacc[1][ct] = MFMA16(ap1, bv, oacc[1][ct]);
            }
        }
    }
    // epilogue: O /= l, store bf16 token-major [b*2048+n][h*64+d]
    int b = bh >> 4, h = bh & 15;
#pragma unroll
    for (int rt = 0; rt < 2; rt++)
#pragma unroll
        for (int r = 0; r < 4; r++) {
            float inv = 1.0f / lrun[rt][r];
            int qrow = qw0 + rt * 16 + quad * 4 + r;
            size_t rowbase = ((size_t)b * 2048 + qrow) * 1024 + h * 64;
#pragma unroll
            for (int ct = 0; ct < 4; ct++)
                o[rowbase + ct * 16 + l16] = f2bf(oacc[rt][ct][r] * inv);
        }
}

extern "C" void kernel_launch(void* const* d_in, const int* in_sizes, int n_in,
                              void* d_out, int out_size, void* d_ws, size_t ws_size,
                              hipStream_t stream) {
    const float* x = (const float*)d_in[0];       // [2,2048,1024]
    const float* gamma = (const float*)d_in[1];   // [1024]
    const float* w_qkv = (const float*)d_in[2];   // [1024,3072]
    const float* w_out = (const float*)d_in[3];   // [1024,1024]
    float* out = (float*)d_out;                   // [2,2048,1024] fp32
    char* ws = (char*)d_ws;

    unsigned short* xn = (unsigned short*)(ws);              // 8 MB (reused as ao)
    unsigned short* wtq = (unsigned short*)(ws + 8388608);   // 6 MB  [3072][1024]
    unsigned short* wto = (unsigned short*)(ws + 14680064);  // 2 MB  [1024][1024]
    unsigned short* qw = (unsigned short*)(ws + 16777216);   // 8 MB  [32][2048][64]
    unsigned short* kw = (unsigned short*)(ws + 25165824);   // 8 MB
    unsigned short* vw = (unsigned short*)(ws + 33554432);   // 8 MB
    unsigned short* ao = xn;                                 // safe reuse after QKV GEMM

    transpose_cast_k<<<dim3(96, 32), 256, 0, stream>>>(w_qkv, wtq, 1024, 3072);
    transpose_cast_k<<<dim3(32, 32), 256, 0, stream>>>(w_out, wto, 1024, 1024);
    rmsnorm_k<<<4096, 256, 0, stream>>>(x, gamma, xn);
    gemm_bt_k<1><<<dim3(24, 32), 256, 0, stream>>>(xn, wtq, nullptr, qw, kw, vw,
                                                   4096, 3072, 1024);
    attn_k<<<dim3(16, 32), 256, 0, stream>>>(qw, kw, vw, ao);
    gemm_bt_k<0><<<dim3(8, 32), 256, 0, stream>>>(ao, wto, out, nullptr, nullptr, nullptr,
                                                  4096, 1024, 1024);
}

// Round 3
// 214.835 us; speedup vs baseline: 1.2986x; 1.2986x over previous
//
#include <hip/hip_runtime.h>
#include <hip/hip_bf16.h>

typedef __bf16 bf16x8 __attribute__((ext_vector_type(8)));
typedef __bf16 bf16x4 __attribute__((ext_vector_type(4)));
typedef short s16x4 __attribute__((ext_vector_type(4)));
typedef float f32x4 __attribute__((ext_vector_type(4)));
typedef unsigned short u16x8 __attribute__((ext_vector_type(8)));

#define MFMA_K32(a, b, c) __builtin_amdgcn_mfma_f32_16x16x32_bf16(a, b, c, 0, 0, 0)

// 16x16x16 bf16 MFMA (A/B = 4 bf16 per lane, k = quad*4 + j).
// Host pass parses this body but never runs it; the builtin only exists
// in the device compilation, hence the __HIP_DEVICE_COMPILE__ guard.
static __device__ __forceinline__ f32x4 mfma_k16(s16x4 a, s16x4 b, f32x4 c) {
#ifdef __HIP_DEVICE_COMPILE__
    return __builtin_amdgcn_mfma_f32_16x16x16bf16_1k(a, b, c, 0, 0, 0);
#else
    return c;
#endif
}

// async global->LDS, 16B per lane; lds dest = wave-uniform base + lane*16
#define GLL16(gp, lp)                                              \
    __builtin_amdgcn_global_load_lds(                              \
        (const __attribute__((address_space(1))) void*)(gp),       \
        (__attribute__((address_space(3))) void*)(lp), 16, 0, 0)

// round-to-nearest-even fp32 -> bf16 (finite inputs only)
static __device__ __forceinline__ unsigned short f2bf(float f) {
    unsigned int u = __float_as_uint(f);
    u += 0x7fffu + ((u >> 16) & 1u);
    return (unsigned short)(u >> 16);
}

// ---------------------------------------------------------------------------
// Tiled transpose + fp32->bf16 cast: in [R x C] fp32 -> out [C x R] bf16
// ---------------------------------------------------------------------------
__global__ __launch_bounds__(256) void transpose_cast_k(
    const float* __restrict__ in, unsigned short* __restrict__ out, int R, int C) {
    __shared__ float t[32][33];
    int c0 = blockIdx.x * 32, r0 = blockIdx.y * 32;
    int tr = threadIdx.x >> 5, tc = threadIdx.x & 31;
#pragma unroll
    for (int i = 0; i < 4; i++)
        t[tr + i * 8][tc] = in[(size_t)(r0 + tr + i * 8) * C + c0 + tc];
    __syncthreads();
#pragma unroll
    for (int i = 0; i < 4; i++)
        out[(size_t)(c0 + tr + i * 8) * R + r0 + tc] = f2bf(t[tc][tr + i * 8]);
}

// ---------------------------------------------------------------------------
// RMSNorm (F.normalize * sqrt(dim) * gamma), fp32 in -> bf16 out. Row = 1024.
// ---------------------------------------------------------------------------
__global__ __launch_bounds__(256) void rmsnorm_k(
    const float* __restrict__ x, const float* __restrict__ gamma,
    unsigned short* __restrict__ xn) {
    int row = blockIdx.x;
    int tid = threadIdx.x;
    const float* xr = x + (size_t)row * 1024;
    float4 v = *(const float4*)(xr + tid * 4);
    float ss = v.x * v.x + v.y * v.y + v.z * v.z + v.w * v.w;
#pragma unroll
    for (int off = 1; off < 64; off <<= 1) ss += __shfl_xor(ss, off, 64);
    __shared__ float red[4];
    if ((tid & 63) == 0) red[tid >> 6] = ss;
    __syncthreads();
    float tot = red[0] + red[1] + red[2] + red[3];
    float f = 32.0f / fmaxf(sqrtf(tot), 1e-12f);  // sqrt(1024)=32
    float4 g = *(const float4*)(gamma + tid * 4);
    ushort4 o;
    o.x = f2bf(v.x * f * g.x);
    o.y = f2bf(v.y * f * g.y);
    o.z = f2bf(v.z * f * g.z);
    o.w = f2bf(v.w * f * g.w);
    *(ushort4*)(xn + (size_t)row * 1024 + tid * 4) = o;
}

// ---------------------------------------------------------------------------
// GEMM (m97 structure): C[M,N] = A[M,K] * BT[N,K]^T, bf16 in, fp32 acc.
// 128x128 tile, BK=32, global_load_lds width-16 staging into unpadded LDS.
// MODE 0: fp32 store. MODE 1: qkv epilogue (q*scale, k in [bh][n][d]; v
// transposed to [bh][d][n] so attention's PV A-operand reads are contiguous).
// ---------------------------------------------------------------------------
template <int MODE>
__global__ __launch_bounds__(256) void gemm_bt_k(
    const unsigned short* __restrict__ A, const unsigned short* __restrict__ BT,
    float* __restrict__ C, unsigned short* __restrict__ qw,
    unsigned short* __restrict__ kw, unsigned short* __restrict__ vw,
    int M, int N, int K) {
    __shared__ unsigned short As[128][32];  // unpadded: global_load_lds layout
    __shared__ unsigned short Bs[128][32];
    int tid = threadIdx.x;
    int wave = tid >> 6, lane = tid & 63, quad = lane >> 4, l16 = lane & 15;
    int wr = wave >> 1, wc = wave & 1;
    int m0 = blockIdx.y * 128, n0 = blockIdx.x * 128;
    int lrow = lane >> 2, lcol = (lane & 3) * 8;  // lane -> (row, col) in 16x32 chunk
    const unsigned short* Ag0 = A + (size_t)(m0 + wave * 32 + lrow) * K + lcol;
    const unsigned short* Ag1 = A + (size_t)(m0 + wave * 32 + 16 + lrow) * K + lcol;
    const unsigned short* Bg0 = BT + (size_t)(n0 + wave * 32 + lrow) * K + lcol;
    const unsigned short* Bg1 = BT + (size_t)(n0 + wave * 32 + 16 + lrow) * K + lcol;
    f32x4 acc[4][4] = {};
    for (int k0 = 0; k0 < K; k0 += 32) {
        __syncthreads();  // prior ds_reads done before overwrite
        GLL16(Ag0 + k0, &As[wave * 32][0]);
        GLL16(Ag1 + k0, &As[wave * 32 + 16][0]);
        GLL16(Bg0 + k0, &Bs[wave * 32][0]);
        GLL16(Bg1 + k0, &Bs[wave * 32 + 16][0]);
        __syncthreads();  // drains vmcnt: staging complete
        bf16x8 af[4], bfr[4];
#pragma unroll
        for (int t = 0; t < 4; t++) {
            af[t] = *(const bf16x8*)&As[wr * 64 + t * 16 + l16][quad * 8];
            bfr[t] = *(const bf16x8*)&Bs[wc * 64 + t * 16 + l16][quad * 8];
        }
#pragma unroll
        for (int rt = 0; rt < 4; rt++)
#pragma unroll
            for (int ct = 0; ct < 4; ct++)
                acc[rt][ct] = MFMA_K32(af[rt], bfr[ct], acc[rt][ct]);
    }
#pragma unroll
    for (int rt = 0; rt < 4; rt++) {
        int mb = m0 + wr * 64 + rt * 16 + quad * 4;
        int b = mb >> 11, nn = mb & 2047;
#pragma unroll
        for (int ct = 0; ct < 4; ct++) {
            int col = n0 + wc * 64 + ct * 16 + l16;
            if (MODE == 0) {
#pragma unroll
                for (int r = 0; r < 4; r++)
                    C[(size_t)(mb + r) * N + col] = acc[rt][ct][r];
            } else {
                int sec = col >> 10, ci = col & 1023;
                int hh = ci >> 6, dd = ci & 63;
                int bh = b * 16 + hh;
                if (sec == 0) {
#pragma unroll
                    for (int r = 0; r < 4; r++)
                        qw[((size_t)bh * 2048 + nn + r) * 64 + dd] = f2bf(acc[rt][ct][r] * 0.125f);
                } else if (sec == 1) {
#pragma unroll
                    for (int r = 0; r < 4; r++)
                        kw[((size_t)bh * 2048 + nn + r) * 64 + dd] = f2bf(acc[rt][ct][r]);
                } else {
                    ushort4 pk;
                    pk.x = f2bf(acc[rt][ct][0]);
                    pk.y = f2bf(acc[rt][ct][1]);
                    pk.z = f2bf(acc[rt][ct][2]);
                    pk.w = f2bf(acc[rt][ct][3]);
                    *(ushort4*)&vw[((size_t)bh * 64 + dd) * 2048 + nn] = pk;
                }
            }
        }
    }
}

// ---------------------------------------------------------------------------
// Causal flash attention, transposed form: St = K*Q^T, Ot = V^T*P^T.
// q,k: [32 bh][2048][64] bf16 (q pre-scaled); vt: [32 bh][64][2048] bf16.
// o: [4096][1024] bf16 token-major.
// Block: 4 waves x 16 q-rows = 64-row q-tile; pair (px, 31-px) -> uniform
// 33 key-tiles per block; 512 blocks. P stays in registers (16x16x16 PV:
// C-layout reg index k=quad*4+r matches the K=16 B-operand layout).
// ---------------------------------------------------------------------------
__global__ __launch_bounds__(256) void attn_k(
    const unsigned short* __restrict__ q, const unsigned short* __restrict__ k,
    const unsigned short* __restrict__ vt, unsigned short* __restrict__ o) {
    __shared__ unsigned short Ks[64][72];  // [key][d], +8 pad: 2-way banks (free)
    __shared__ unsigned short Vt[64][72];  // [d][key]
    int bh = blockIdx.y, px = blockIdx.x;
    int tid = threadIdx.x, wave = tid >> 6, lane = tid & 63;
    int quad = lane >> 4, l16 = lane & 15;
    int b = bh >> 4, h = bh & 15;
    const unsigned short* qg = q + (size_t)bh * 2048 * 64;
    const unsigned short* kg = k + (size_t)bh * 2048 * 64;
    const unsigned short* vg = vt + (size_t)bh * 64 * 2048;
    int srow = tid >> 2, scol = (tid & 3) * 16;
#pragma unroll 1
    for (int phase = 0; phase < 2; phase++) {
        int qt = phase == 0 ? (31 - px) : px;  // paired tiles: uniform 33 iters
        int q0w = qt * 64 + wave * 16;
        bf16x8 bq[2];  // Q^T B-operand: [k=d=ks*32+quad*8+j][n=qrow=l16]
#pragma unroll
        for (int ks = 0; ks < 2; ks++)
            bq[ks] = *(const bf16x8*)&qg[(size_t)(q0w + l16) * 64 + ks * 32 + quad * 8];
        f32x4 ot[4] = {};                 // Ot C-layout: [d=dt*16+quad*4+r][qrow=l16]
        float mrun = -1e38f, lrun = 0.f;  // per-lane state for qrow=q0w+l16
        int nkt = qt + 1;
        for (int kt = 0; kt < nkt; kt++) {
            __syncthreads();  // prev tile's LDS reads done
            *(u16x8*)&Ks[srow][scol] = *(const u16x8*)&kg[(size_t)(kt * 64 + srow) * 64 + scol];
            *(u16x8*)&Ks[srow][scol + 8] = *(const u16x8*)&kg[(size_t)(kt * 64 + srow) * 64 + scol + 8];
            *(u16x8*)&Vt[srow][scol] = *(const u16x8*)&vg[(size_t)srow * 2048 + kt * 64 + scol];
            *(u16x8*)&Vt[srow][scol + 8] = *(const u16x8*)&vg[(size_t)srow * 2048 + kt * 64 + scol + 8];
            __syncthreads();  // staging visible
            // St[key=ct*16+quad*4+r][qrow=l16] = K . Q^T
            f32x4 sf[4];
#pragma unroll
            for (int ct = 0; ct < 4; ct++) {
                bf16x8 ak0 = *(const bf16x8*)&Ks[ct * 16 + l16][quad * 8];
                bf16x8 ak1 = *(const bf16x8*)&Ks[ct * 16 + l16][32 + quad * 8];
                f32x4 s = {};
                s = MFMA_K32(ak0, bq[0], s);
                s = MFMA_K32(ak1, bq[1], s);
                sf[ct] = s;
            }
            if (kt == qt) {  // diagonal tile: causal mask (local indices)
                int qloc = wave * 16 + l16;
#pragma unroll
                for (int ct = 0; ct < 4; ct++)
#pragma unroll
                    for (int r = 0; r < 4; r++)
                        if (ct * 16 + quad * 4 + r > qloc) sf[ct][r] = -1e30f;
            }
            // online softmax along keys: per-lane over 16 regs, then quads
            float mx = -1e30f;
#pragma unroll
            for (int ct = 0; ct < 4; ct++)
#pragma unroll
                for (int r = 0; r < 4; r++) mx = fmaxf(mx, sf[ct][r]);
            mx = fmaxf(mx, __shfl_xor(mx, 16, 64));
            mx = fmaxf(mx, __shfl_xor(mx, 32, 64));
            float mnew = fmaxf(mrun, mx);
            float al = __expf(mrun - mnew);
            mrun = mnew;
            float rs = 0.f;
#pragma unroll
            for (int ct = 0; ct < 4; ct++)
#pragma unroll
                for (int r = 0; r < 4; r++) {
                    float p = __expf(sf[ct][r] - mnew);
                    sf[ct][r] = p;
                    rs += p;
                }
            rs += __shfl_xor(rs, 16, 64);
            rs += __shfl_xor(rs, 32, 64);
            lrun = lrun * al + rs;
            // P -> bf16 B-fragments for 16x16x16 (k=quad*4+j matches C-layout)
            s16x4 bpr[4];
#pragma unroll
            for (int ct = 0; ct < 4; ct++) {
#pragma unroll
                for (int r = 0; r < 4; r++) bpr[ct][r] = (short)f2bf(sf[ct][r]);
            }
            // rescale Ot, then Ot += V^T * P^T
#pragma unroll
            for (int dt = 0; dt < 4; dt++) {
#pragma unroll
                for (int r = 0; r < 4; r++) ot[dt][r] *= al;
#pragma unroll
                for (int ct = 0; ct < 4; ct++) {
                    s16x4 av = *(const s16x4*)&Vt[dt * 16 + l16][ct * 16 + quad * 4];
                    ot[dt] = mfma_k16(av, bpr[ct], ot[dt]);
                }
            }
        }
        // epilogue: Ot C-layout -> o[(b*2048+qrow)*1024 + h*64 + d], ushort4
        float inv = 1.0f / lrun;
        size_t rowbase = ((size_t)b * 2048 + q0w + l16) * 1024 + h * 64;
#pragma unroll
        for (int dt = 0; dt < 4; dt++) {
            ushort4 pk;
            pk.x = f2bf(ot[dt][0] * inv);
            pk.y = f2bf(ot[dt][1] * inv);
            pk.z = f2bf(ot[dt][2] * inv);
            pk.w = f2bf(ot[dt][3] * inv);
            *(ushort4*)&o[rowbase + dt * 16 + quad * 4] = pk;
        }
    }
}

extern "C" void kernel_launch(void* const* d_in, const int* in_sizes, int n_in,
                              void* d_out, int out_size, void* d_ws, size_t ws_size,
                              hipStream_t stream) {
    const float* x = (const float*)d_in[0];       // [2,2048,1024]
    const float* gamma = (const float*)d_in[1];   // [1024]
    const float* w_qkv = (const float*)d_in[2];   // [1024,3072]
    const float* w_out = (const float*)d_in[3];   // [1024,1024]
    float* out = (float*)d_out;                   // [2,2048,1024] fp32
    char* ws = (char*)d_ws;

    unsigned short* xn = (unsigned short*)(ws);              // 8 MB (reused as ao)
    unsigned short* wtq = (unsigned short*)(ws + 8388608);   // 6 MB  [3072][1024]
    unsigned short* wto = (unsigned short*)(ws + 14680064);  // 2 MB  [1024][1024]
    unsigned short* qw = (unsigned short*)(ws + 16777216);   // 8 MB  [32][2048][64]
    unsigned short* kw = (unsigned short*)(ws + 25165824);   // 8 MB  [32][2048][64]
    unsigned short* vw = (unsigned short*)(ws + 33554432);   // 8 MB  [32][64][2048]
    unsigned short* ao = xn;                                 // reuse after QKV GEMM

    transpose_cast_k<<<dim3(96, 32), 256, 0, stream>>>(w_qkv, wtq, 1024, 3072);
    transpose_cast_k<<<dim3(32, 32), 256, 0, stream>>>(w_out, wto, 1024, 1024);
    rmsnorm_k<<<4096, 256, 0, stream>>>(x, gamma, xn);
    gemm_bt_k<1><<<dim3(24, 32), 256, 0, stream>>>(xn, wtq, nullptr, qw, kw, vw,
                                                   4096, 3072, 1024);
    attn_k<<<dim3(16, 32), 256, 0, stream>>>(qw, kw, vw, ao);
    gemm_bt_k<0><<<dim3(8, 32), 256, 0, stream>>>(ao, wto, out, nullptr, nullptr, nullptr,
                                                  4096, 1024, 1024);
}

// Round 4
// 195.411 us; speedup vs baseline: 1.4277x; 1.0994x over previous
//
#include <hip/hip_runtime.h>
#include <hip/hip_bf16.h>

typedef __bf16 bf16x8 __attribute__((ext_vector_type(8)));
typedef short s16x4 __attribute__((ext_vector_type(4)));
typedef float f32x4 __attribute__((ext_vector_type(4)));
typedef unsigned short u16x8 __attribute__((ext_vector_type(8)));

#define MFMA_K32(a, b, c) __builtin_amdgcn_mfma_f32_16x16x32_bf16(a, b, c, 0, 0, 0)

// 16x16x16 bf16 MFMA; builtin exists only in device pass.
static __device__ __forceinline__ f32x4 mfma_k16(s16x4 a, s16x4 b, f32x4 c) {
#ifdef __HIP_DEVICE_COMPILE__
    return __builtin_amdgcn_mfma_f32_16x16x16bf16_1k(a, b, c, 0, 0, 0);
#else
    return c;
#endif
}

static __device__ __forceinline__ float fast_exp2(float x) {
#ifdef __HIP_DEVICE_COMPILE__
    return __builtin_amdgcn_exp2f(x);
#else
    return x;
#endif
}

// async global->LDS, 16B per lane; lds dest = wave-uniform base + lane*16
#define GLL16(gp, lp)                                              \
    __builtin_amdgcn_global_load_lds(                              \
        (const __attribute__((address_space(1))) void*)(gp),       \
        (__attribute__((address_space(3))) void*)(lp), 16, 0, 0)

// round-to-nearest-even fp32 -> bf16 (finite inputs only)
static __device__ __forceinline__ unsigned short f2bf(float f) {
    unsigned int u = __float_as_uint(f);
    u += 0x7fffu + ((u >> 16) & 1u);
    return (unsigned short)(u >> 16);
}

// packed fp32x2 -> bf16x2 (RNE) via gfx950 v_cvt_pk_bf16_f32 when available
static __device__ __forceinline__ unsigned int cvtpk_bf16(float lo, float hi) {
#if defined(__HIP_DEVICE_COMPILE__) && __has_builtin(__builtin_amdgcn_cvt_pk_bf16_f32)
    typedef __bf16 bf16x2 __attribute__((ext_vector_type(2)));
    bf16x2 r = __builtin_amdgcn_cvt_pk_bf16_f32(lo, hi);
    return __builtin_bit_cast(unsigned int, r);
#else
    return (unsigned int)f2bf(lo) | ((unsigned int)f2bf(hi) << 16);
#endif
}

#define LOG2E 1.44269504088896340736f

// ---------------------------------------------------------------------------
// Fused prep: transpose+cast w_qkv and w_out, rmsnorm x -> xn (bf16).
// bid < 3072: w_qkv tile; < 4096: w_out tile; else rmsnorm row (bid-4096).
// ---------------------------------------------------------------------------
__global__ __launch_bounds__(256) void prep_k(
    const float* __restrict__ x, const float* __restrict__ gamma,
    const float* __restrict__ w_qkv, const float* __restrict__ w_out,
    unsigned short* __restrict__ xn, unsigned short* __restrict__ wtq,
    unsigned short* __restrict__ wto) {
    __shared__ float sm[32][33];
    int bid = blockIdx.x, tid = threadIdx.x;
    if (bid < 4096) {  // transpose paths (block-uniform branch)
        const float* in;
        unsigned short* out;
        int R = 1024, C, bx, by;
        if (bid < 3072) { in = w_qkv; out = wtq; C = 3072; bx = bid % 96; by = bid / 96; }
        else { int b2 = bid - 3072; in = w_out; out = wto; C = 1024; bx = b2 % 32; by = b2 / 32; }
        int c0 = bx * 32, r0 = by * 32;
        int tr = tid >> 5, tc = tid & 31;
#pragma unroll
        for (int i = 0; i < 4; i++)
            sm[tr + i * 8][tc] = in[(size_t)(r0 + tr + i * 8) * C + c0 + tc];
        __syncthreads();
#pragma unroll
        for (int i = 0; i < 4; i++)
            out[(size_t)(c0 + tr + i * 8) * R + r0 + tc] = f2bf(sm[tc][tr + i * 8]);
    } else {  // rmsnorm
        int row = bid - 4096;
        const float* xr = x + (size_t)row * 1024;
        float4 v = *(const float4*)(xr + tid * 4);
        float ss = v.x * v.x + v.y * v.y + v.z * v.z + v.w * v.w;
#pragma unroll
        for (int off = 1; off < 64; off <<= 1) ss += __shfl_xor(ss, off, 64);
        if ((tid & 63) == 0) sm[0][tid >> 6] = ss;
        __syncthreads();
        float tot = sm[0][0] + sm[0][1] + sm[0][2] + sm[0][3];
        float f = 32.0f / fmaxf(sqrtf(tot), 1e-12f);  // sqrt(1024)=32
        float4 g = *(const float4*)(gamma + tid * 4);
        uint2 o;
        o.x = cvtpk_bf16(v.x * f * g.x, v.y * f * g.y);
        o.y = cvtpk_bf16(v.z * f * g.z, v.w * f * g.w);
        *(uint2*)(xn + (size_t)row * 1024 + tid * 4) = o;
    }
}

// ---------------------------------------------------------------------------
// GEMM (m97 structure): C[M,N] = A[M,K] * BT[N,K]^T, bf16 in, fp32 acc.
// BM x 128 tile, BK=32, global_load_lds width-16 staging into unpadded LDS.
// BM=128: 4 waves 2x2 (4x4 frags). BM=64: 4 waves 1x4 (4x2 frags).
// MODE 0: fp32 store. MODE 1: qkv epilogue (q * scale*log2e for exp2-domain
// softmax; k in [bh][n][d]; v transposed to [bh][d][n]).
// ---------------------------------------------------------------------------
template <int MODE, int BM>
__global__ __launch_bounds__(256) void gemm_bt_k(
    const unsigned short* __restrict__ A, const unsigned short* __restrict__ BT,
    float* __restrict__ C, unsigned short* __restrict__ qw,
    unsigned short* __restrict__ kw, unsigned short* __restrict__ vw,
    int M, int N, int K) {
    constexpr int RT = 4;
    constexpr int CT = (BM == 128) ? 4 : 2;
    __shared__ unsigned short As[BM][32];
    __shared__ unsigned short Bs[128][32];
    int tid = threadIdx.x;
    int wave = tid >> 6, lane = tid & 63, quad = lane >> 4, l16 = lane & 15;
    int wrb, wcb;
    if constexpr (BM == 128) { wrb = (wave >> 1) * 64; wcb = (wave & 1) * 64; }
    else { wrb = 0; wcb = wave * 32; }
    int m0 = blockIdx.y * BM, n0 = blockIdx.x * 128;
    int lrow = lane >> 2, lcol = (lane & 3) * 8;  // lane -> (row,col) in 16x32 chunk
    const unsigned short *Ag0, *Ag1 = nullptr;
    if constexpr (BM == 128) {
        Ag0 = A + (size_t)(m0 + wave * 32 + lrow) * K + lcol;
        Ag1 = A + (size_t)(m0 + wave * 32 + 16 + lrow) * K + lcol;
    } else {
        Ag0 = A + (size_t)(m0 + wave * 16 + lrow) * K + lcol;
    }
    const unsigned short* Bg0 = BT + (size_t)(n0 + wave * 32 + lrow) * K + lcol;
    const unsigned short* Bg1 = BT + (size_t)(n0 + wave * 32 + 16 + lrow) * K + lcol;
    f32x4 acc[RT][CT] = {};
    for (int k0 = 0; k0 < K; k0 += 32) {
        __syncthreads();  // prior ds_reads done before overwrite
        if constexpr (BM == 128) {
            GLL16(Ag0 + k0, &As[wave * 32][0]);
            GLL16(Ag1 + k0, &As[wave * 32 + 16][0]);
        } else {
            GLL16(Ag0 + k0, &As[wave * 16][0]);
        }
        GLL16(Bg0 + k0, &Bs[wave * 32][0]);
        GLL16(Bg1 + k0, &Bs[wave * 32 + 16][0]);
        __syncthreads();  // drains vmcnt: staging complete
        bf16x8 af[RT], bfr[CT];
#pragma unroll
        for (int t = 0; t < RT; t++)
            af[t] = *(const bf16x8*)&As[wrb + t * 16 + l16][quad * 8];
#pragma unroll
        for (int t = 0; t < CT; t++)
            bfr[t] = *(const bf16x8*)&Bs[wcb + t * 16 + l16][quad * 8];
#pragma unroll
        for (int rt = 0; rt < RT; rt++)
#pragma unroll
            for (int ct = 0; ct < CT; ct++)
                acc[rt][ct] = MFMA_K32(af[rt], bfr[ct], acc[rt][ct]);
    }
#pragma unroll
    for (int rt = 0; rt < RT; rt++) {
        int mb = m0 + wrb + rt * 16 + quad * 4;
        int b = mb >> 11, nn = mb & 2047;
#pragma unroll
        for (int ct = 0; ct < CT; ct++) {
            int col = n0 + wcb + ct * 16 + l16;
            if (MODE == 0) {
#pragma unroll
                for (int r = 0; r < 4; r++)
                    C[(size_t)(mb + r) * N + col] = acc[rt][ct][r];
            } else {
                int sec = col >> 10, ci = col & 1023;
                int hh = ci >> 6, dd = ci & 63;
                int bh = b * 16 + hh;
                if (sec == 0) {
#pragma unroll
                    for (int r = 0; r < 4; r++)
                        qw[((size_t)bh * 2048 + nn + r) * 64 + dd] =
                            f2bf(acc[rt][ct][r] * (0.125f * LOG2E));
                } else if (sec == 1) {
#pragma unroll
                    for (int r = 0; r < 4; r++)
                        kw[((size_t)bh * 2048 + nn + r) * 64 + dd] = f2bf(acc[rt][ct][r]);
                } else {
                    uint2 pk;
                    pk.x = cvtpk_bf16(acc[rt][ct][0], acc[rt][ct][1]);
                    pk.y = cvtpk_bf16(acc[rt][ct][2], acc[rt][ct][3]);
                    *(uint2*)&vw[((size_t)bh * 64 + dd) * 2048 + nn] = pk;
                }
            }
        }
    }
}

// ---------------------------------------------------------------------------
// Causal flash attention, transposed form: St = K*Q^T, Ot = V^T*P^T.
// q,k: [32 bh][2048][64] bf16 (q pre-scaled by 0.125*log2e -> exp2 softmax);
// vt: [32 bh][64][2048] bf16. o: [4096][1024] bf16 token-major.
// 4 waves x 16 q-rows = 64-row q-tile; pair (px, 31-px) -> uniform 33
// key-tiles/block; 512 blocks. Double-buffered K/V LDS, register prefetch,
// ONE barrier per key-tile. P stays in registers (16x16x16 PV).
// ---------------------------------------------------------------------------
__global__ __launch_bounds__(256) void attn_k(
    const unsigned short* __restrict__ q, const unsigned short* __restrict__ k,
    const unsigned short* __restrict__ vt, unsigned short* __restrict__ o) {
    __shared__ unsigned short Ks[2][64][72];  // [buf][key][d]
    __shared__ unsigned short Vt[2][64][72];  // [buf][d][key]
    int bh = blockIdx.y, px = blockIdx.x;
    int tid = threadIdx.x, wave = tid >> 6, lane = tid & 63;
    int quad = lane >> 4, l16 = lane & 15;
    int b = bh >> 4, h = bh & 15;
    const unsigned short* qg = q + (size_t)bh * 2048 * 64;
    const unsigned short* kg = k + (size_t)bh * 2048 * 64;
    const unsigned short* vg = vt + (size_t)bh * 64 * 2048;
    int srow = tid >> 2, scol = (tid & 3) * 16;
    u16x8 pk0, pk1, pv0, pv1;  // prefetch registers
#pragma unroll 1
    for (int phase = 0; phase < 2; phase++) {
        int qt = phase == 0 ? (31 - px) : px;  // paired tiles: uniform 33 iters
        int q0w = qt * 64 + wave * 16;
        bf16x8 bq[2];  // Q^T B-operand: [k=d=ks*32+quad*8+j][n=qrow=l16]
#pragma unroll
        for (int ks = 0; ks < 2; ks++)
            bq[ks] = *(const bf16x8*)&qg[(size_t)(q0w + l16) * 64 + ks * 32 + quad * 8];
        f32x4 ot[4] = {};                 // Ot C-layout: [d=dt*16+quad*4+r][qrow=l16]
        float mrun = -1e38f, lrun = 0.f;  // per-lane state for qrow=q0w+l16
        int nkt = qt + 1;
        // preload tile 0
        {
            const unsigned short* kp = kg + (size_t)srow * 64 + scol;
            pk0 = *(const u16x8*)kp;
            pk1 = *(const u16x8*)(kp + 8);
            const unsigned short* vp = vg + (size_t)srow * 2048 + scol;
            pv0 = *(const u16x8*)vp;
            pv1 = *(const u16x8*)(vp + 8);
            *(u16x8*)&Ks[0][srow][scol] = pk0;
            *(u16x8*)&Ks[0][srow][scol + 8] = pk1;
            *(u16x8*)&Vt[0][srow][scol] = pv0;
            *(u16x8*)&Vt[0][srow][scol + 8] = pv1;
        }
        __syncthreads();
        for (int kt = 0; kt < nkt; kt++) {
            int cb = kt & 1;
            bool pf = (kt + 1 < nkt);
            if (pf) {  // issue next tile's global loads early (wave-uniform branch)
                const unsigned short* kp = kg + (size_t)((kt + 1) * 64 + srow) * 64 + scol;
                pk0 = *(const u16x8*)kp;
                pk1 = *(const u16x8*)(kp + 8);
                const unsigned short* vp = vg + (size_t)srow * 2048 + (kt + 1) * 64 + scol;
                pv0 = *(const u16x8*)vp;
                pv1 = *(const u16x8*)(vp + 8);
            }
            // St[key=ct*16+quad*4+r][qrow=l16] = K . Q^T
            f32x4 sf[4];
#pragma unroll
            for (int ct = 0; ct < 4; ct++) {
                bf16x8 ak0 = *(const bf16x8*)&Ks[cb][ct * 16 + l16][quad * 8];
                bf16x8 ak1 = *(const bf16x8*)&Ks[cb][ct * 16 + l16][32 + quad * 8];
                f32x4 s = {};
                s = MFMA_K32(ak0, bq[0], s);
                s = MFMA_K32(ak1, bq[1], s);
                sf[ct] = s;
            }
            if (kt == qt) {  // diagonal tile: causal mask (local indices)
                int qloc = wave * 16 + l16;
#pragma unroll
                for (int ct = 0; ct < 4; ct++)
#pragma unroll
                    for (int r = 0; r < 4; r++)
                        if (ct * 16 + quad * 4 + r > qloc) sf[ct][r] = -1e30f;
            }
            // online softmax (exp2 domain; log2e pre-folded into q)
            float mx = -1e30f;
#pragma unroll
            for (int ct = 0; ct < 4; ct++)
#pragma unroll
                for (int r = 0; r < 4; r++) mx = fmaxf(mx, sf[ct][r]);
            mx = fmaxf(mx, __shfl_xor(mx, 16, 64));
            mx = fmaxf(mx, __shfl_xor(mx, 32, 64));
            float mnew = fmaxf(mrun, mx);
            float al = fast_exp2(mrun - mnew);
            mrun = mnew;
            float rs = 0.f;
#pragma unroll
            for (int ct = 0; ct < 4; ct++)
#pragma unroll
                for (int r = 0; r < 4; r++) {
                    float p = fast_exp2(sf[ct][r] - mnew);
                    sf[ct][r] = p;
                    rs += p;
                }
            rs += __shfl_xor(rs, 16, 64);
            rs += __shfl_xor(rs, 32, 64);
            lrun = lrun * al + rs;
            // P -> packed bf16 B-fragments for 16x16x16 (k=quad*4+j = C-layout)
            s16x4 bpr[4];
#pragma unroll
            for (int ct = 0; ct < 4; ct++) {
                uint2 u;
                u.x = cvtpk_bf16(sf[ct][0], sf[ct][1]);
                u.y = cvtpk_bf16(sf[ct][2], sf[ct][3]);
                bpr[ct] = __builtin_bit_cast(s16x4, u);
            }
            // rescale Ot, then Ot += V^T * P^T
#pragma unroll
            for (int dt = 0; dt < 4; dt++) {
#pragma unroll
                for (int r = 0; r < 4; r++) ot[dt][r] *= al;
#pragma unroll
                for (int ct = 0; ct < 4; ct++) {
                    s16x4 av = *(const s16x4*)&Vt[cb][dt * 16 + l16][ct * 16 + quad * 4];
                    ot[dt] = mfma_k16(av, bpr[ct], ot[dt]);
                }
            }
            if (pf) {  // write prefetched tile to the other buffer
                *(u16x8*)&Ks[1 - cb][srow][scol] = pk0;
                *(u16x8*)&Ks[1 - cb][srow][scol + 8] = pk1;
                *(u16x8*)&Vt[1 - cb][srow][scol] = pv0;
                *(u16x8*)&Vt[1 - cb][srow][scol + 8] = pv1;
            }
            __syncthreads();  // single barrier per tile
        }
        // epilogue: Ot C-layout -> o[(b*2048+qrow)*1024 + h*64 + d]
        float inv = 1.0f / lrun;
        size_t rowbase = ((size_t)b * 2048 + q0w + l16) * 1024 + h * 64;
#pragma unroll
        for (int dt = 0; dt < 4; dt++) {
            uint2 pk;
            pk.x = cvtpk_bf16(ot[dt][0] * inv, ot[dt][1] * inv);
            pk.y = cvtpk_bf16(ot[dt][2] * inv, ot[dt][3] * inv);
            *(uint2*)&o[rowbase + dt * 16 + quad * 4] = pk;
        }
    }
}

extern "C" void kernel_launch(void* const* d_in, const int* in_sizes, int n_in,
                              void* d_out, int out_size, void* d_ws, size_t ws_size,
                              hipStream_t stream) {
    const float* x = (const float*)d_in[0];       // [2,2048,1024]
    const float* gamma = (const float*)d_in[1];   // [1024]
    const float* w_qkv = (const float*)d_in[2];   // [1024,3072]
    const float* w_out = (const float*)d_in[3];   // [1024,1024]
    float* out = (float*)d_out;                   // [2,2048,1024] fp32
    char* ws = (char*)d_ws;

    unsigned short* xn = (unsigned short*)(ws);              // 8 MB (reused as ao)
    unsigned short* wtq = (unsigned short*)(ws + 8388608);   // 6 MB  [3072][1024]
    unsigned short* wto = (unsigned short*)(ws + 14680064);  // 2 MB  [1024][1024]
    unsigned short* qw = (unsigned short*)(ws + 16777216);   // 8 MB  [32][2048][64]
    unsigned short* kw = (unsigned short*)(ws + 25165824);   // 8 MB  [32][2048][64]
    unsigned short* vw = (unsigned short*)(ws + 33554432);   // 8 MB  [32][64][2048]
    unsigned short* ao = xn;                                 // reuse after QKV GEMM

    prep_k<<<8192, 256, 0, stream>>>(x, gamma, w_qkv, w_out, xn, wtq, wto);
    gemm_bt_k<1, 128><<<dim3(24, 32), 256, 0, stream>>>(xn, wtq, nullptr, qw, kw, vw,
                                                        4096, 3072, 1024);
    attn_k<<<dim3(16, 32), 256, 0, stream>>>(qw, kw, vw, ao);
    gemm_bt_k<0, 64><<<dim3(8, 64), 256, 0, stream>>>(ao, wto, out, nullptr, nullptr,
                                                      nullptr, 4096, 1024, 1024);
}